// Round 5
// baseline (259.111 us; speedup 1.0000x reference)
//
#include <hip/hip_runtime.h>

#define NN 8000
#define FD 256
#define NEG_SLOPE 0.2f
#define BM 32
#define KT 160
#define NSPLIT 5
#define JQ (NN / NSPLIT)      // 1600
#define NS (JQ / KT)          // 10
#define WROWB 336             // padded Wt row stride in BYTES (168 bf16, 84 words)
#define WTB (BM * WROWB)      // 10752 bytes per Wt buffer

typedef __bf16 bf16;
typedef __bf16 bf16x8 __attribute__((ext_vector_type(8)));
typedef float f32x4 __attribute__((ext_vector_type(4)));

// ---------------- K1: H = X @ W^T + b -> Ht (bf16, transposed [f][i]) ----------------
__global__ __launch_bounds__(256) void k_linear(const float* __restrict__ X,
                                                const float* __restrict__ W,
                                                const float* __restrict__ b,
                                                bf16* __restrict__ Ht) {
    __shared__ float Xs[16][260];
    const int t = threadIdx.x;
    const int i0 = blockIdx.x * 16;
    #pragma unroll
    for (int r = 0; r < 16; ++r)
        Xs[r][t] = X[(size_t)(i0 + r) * FD + t];
    __syncthreads();
    const int f = t;
    float acc[16];
    const float bf_ = b[f];
    #pragma unroll
    for (int ii = 0; ii < 16; ++ii) acc[ii] = bf_;
    for (int k4 = 0; k4 < FD / 4; ++k4) {
        const float4 w4 = *(const float4*)&W[(size_t)f * FD + k4 * 4];
        #pragma unroll
        for (int ii = 0; ii < 16; ++ii) {
            const float4 x4 = *(const float4*)&Xs[ii][k4 * 4];
            acc[ii] += x4.x * w4.x + x4.y * w4.y + x4.z * w4.z + x4.w * w4.w;
        }
    }
    bf16x8 v0, v1;
    #pragma unroll
    for (int ii = 0; ii < 8; ++ii) { v0[ii] = (bf16)acc[ii]; v1[ii] = (bf16)acc[ii + 8]; }
    *(bf16x8*)&Ht[(size_t)f * NN + i0]     = v0;
    *(bf16x8*)&Ht[(size_t)f * NN + i0 + 8] = v1;
}

// ---------------- K2: hs = H@a_src + a_b, hd = H@a_dst ----------------
__global__ __launch_bounds__(256) void k_attn_vec(const bf16* __restrict__ Ht,
                                                  const float* __restrict__ a_src,
                                                  const float* __restrict__ a_dst,
                                                  const float* __restrict__ a_b,
                                                  float* __restrict__ hs,
                                                  float* __restrict__ hd) {
    __shared__ float psh[4][64], pdh[4][64];
    const int t = threadIdx.x;
    const int li = t & 63;
    const int q = t >> 6;
    const int i = blockIdx.x * 64 + li;
    float ps = 0.f, pd = 0.f;
    #pragma unroll 8
    for (int fi = 0; fi < 64; ++fi) {
        const int f = q * 64 + fi;
        const float h = (float)Ht[(size_t)f * NN + i];
        ps += h * a_src[f];
        pd += h * a_dst[f];
    }
    psh[q][li] = ps; pdh[q][li] = pd;
    __syncthreads();
    if (q == 0) {
        ps = psh[0][li] + psh[1][li] + psh[2][li] + psh[3][li];
        pd = pdh[0][li] + pdh[1][li] + pdh[2][li] + pdh[3][li];
        hs[i] = ps + a_b[0];
        hd[i] = pd;
    }
}

__device__ __forceinline__ bf16x8 wcompute(int4 alo, int4 ahi, float4 hlo, float4 hhi,
                                           float hsv, float& ls) {
    float w[8]; float e;
    e = hsv + hlo.x; e = e >= 0.f ? e : NEG_SLOPE * e; w[0] = alo.x ? __expf(e) : 0.f;
    e = hsv + hlo.y; e = e >= 0.f ? e : NEG_SLOPE * e; w[1] = alo.y ? __expf(e) : 0.f;
    e = hsv + hlo.z; e = e >= 0.f ? e : NEG_SLOPE * e; w[2] = alo.z ? __expf(e) : 0.f;
    e = hsv + hlo.w; e = e >= 0.f ? e : NEG_SLOPE * e; w[3] = alo.w ? __expf(e) : 0.f;
    e = hsv + hhi.x; e = e >= 0.f ? e : NEG_SLOPE * e; w[4] = ahi.x ? __expf(e) : 0.f;
    e = hsv + hhi.y; e = e >= 0.f ? e : NEG_SLOPE * e; w[5] = ahi.y ? __expf(e) : 0.f;
    e = hsv + hhi.z; e = e >= 0.f ? e : NEG_SLOPE * e; w[6] = ahi.z ? __expf(e) : 0.f;
    e = hsv + hhi.w; e = e >= 0.f ? e : NEG_SLOPE * e; w[7] = ahi.w ? __expf(e) : 0.f;
    ls += ((w[0] + w[1]) + (w[2] + w[3])) + ((w[4] + w[5]) + (w[6] + w[7]));
    bf16x8 r;
    #pragma unroll
    for (int i = 0; i < 8; ++i) r[i] = (bf16)w[i];
    return r;
}

// ---------------- K3: fused weights + MFMA PV, split-j x5, 10 big steps --------
// 512 thr (8 waves), BM=32 rows, KT=160 j per step. A-tile (weights) in LDS
// with PADDED row stride (336 B -> 2-way max bank aliasing, no swizzle),
// double-buffered, ONE raw barrier per step; B-frags global->register from
// L2-resident Ht; adj/hd prefetch one full step ahead.
__global__ __launch_bounds__(512, 4) void k_gat(const bf16* __restrict__ Ht,
                                                const int* __restrict__ adj,
                                                const float* __restrict__ hs,
                                                const float* __restrict__ hd,
                                                float* __restrict__ out,
                                                float* __restrict__ lg) {
    __shared__ __attribute__((aligned(16))) char Wt[2][WTB];   // 2 x 10.5 KB
    __shared__ float lrow[BM];

    const int t  = threadIdx.x;
    const int l  = t & 63;
    const int wv = t >> 6;
    const int bid = blockIdx.x;
    const int ib = bid % (NN / BM);      // 0..249
    const int jb = bid / (NN / BM);      // 0..4
    const int i0 = ib * BM;
    const int jq0 = jb * JQ;

    // ---- weight-unit mapping: 640 units of 8 j's; unit u -> row u/20, slot u%20
    const int r0 = t / 20, s0 = t % 20;
    const bool has2 = (t & 3) == 0;
    const int u1 = 512 + (t >> 2);       // threads t%4==0 take the 128 tail units
    const int r1 = u1 / 20, s1 = u1 % 20;

    const float hsv0 = hs[i0 + r0];
    const float hsv1 = has2 ? hs[i0 + r1] : 0.f;

    const int*   adjp0 = adj + (size_t)(i0 + r0) * NN + jq0 + s0 * 8;
    const int*   adjp1 = adj + (size_t)(i0 + r1) * NN + jq0 + s1 * 8;
    const float* hdp0  = hd + jq0 + s0 * 8;
    const float* hdp1  = hd + jq0 + s1 * 8;
    const int w0off = r0 * WROWB + s0 * 16;   // byte offsets, writer == reader formula
    const int w1off = r1 * WROWB + s1 * 16;

    // ---- MFMA mapping
    const int al = l & 15, asl = l >> 4;
    const int a0base = al * WROWB + asl * 16;          // + k*64 at read
    const int a1base = (al + 16) * WROWB + asl * 16;
    const bf16* bpA = Ht + (size_t)(wv * 32 + al) * NN + jq0 + asl * 8;
    const bf16* bpB = bpA + (size_t)16 * NN;

    char* const wtb = (char*)Wt;

    if (t < BM) lrow[t] = 0.f;

    float lsum0 = 0.f, lsum1 = 0.f;

    // ---- prologue: weights(0) -> Wt[0]
    {
        int4 alo = *(const int4*)adjp0;
        int4 ahi = *(const int4*)(adjp0 + 4);
        float4 hlo = *(const float4*)hdp0;
        float4 hhi = *(const float4*)(hdp0 + 4);
        bf16x8 wv8 = wcompute(alo, ahi, hlo, hhi, hsv0, lsum0);
        *(bf16x8*)(wtb + w0off) = wv8;
        if (has2) {
            alo = *(const int4*)adjp1;
            ahi = *(const int4*)(adjp1 + 4);
            hlo = *(const float4*)hdp1;
            hhi = *(const float4*)(hdp1 + 4);
            wv8 = wcompute(alo, ahi, hlo, hhi, hsv1, lsum1);
            *(bf16x8*)(wtb + w1off) = wv8;
        }
    }
    __syncthreads();

    f32x4 acc00 = {0.f, 0.f, 0.f, 0.f}, acc01 = acc00, acc10 = acc00, acc11 = acc00;

    #pragma unroll 1
    for (int s = 0; s < NS; ++s) {
        const int cur = s & 1;
        char* const wb = wtb + cur * WTB;
        char* const wn = wtb + (cur ^ 1) * WTB;
        const bool haveN = (s + 1 < NS);

        // issue adj/hd loads for step s+1 (HBM long pole first)
        int4 alo0, ahi0, alo1, ahi1;
        float4 hlo0, hhi0, hlo1, hhi1;
        if (haveN) {
            const int off = (s + 1) * KT;
            alo0 = *(const int4*)(adjp0 + off);
            ahi0 = *(const int4*)(adjp0 + off + 4);
            hlo0 = *(const float4*)(hdp0 + off);
            hhi0 = *(const float4*)(hdp0 + off + 4);
            if (has2) {
                alo1 = *(const int4*)(adjp1 + off);
                ahi1 = *(const int4*)(adjp1 + off + 4);
                hlo1 = *(const float4*)(hdp1 + off);
                hhi1 = *(const float4*)(hdp1 + off + 4);
            }
        }

        // issue B loads for this step (L2)
        bf16x8 b[2][5];
        #pragma unroll
        for (int k = 0; k < 5; ++k) {
            b[0][k] = *(const bf16x8*)(bpA + (size_t)s * KT + k * 32);
            b[1][k] = *(const bf16x8*)(bpB + (size_t)s * KT + k * 32);
        }

        // MFMA phase: 20 MFMA over 5 k-subtiles
        #pragma unroll
        for (int k = 0; k < 5; ++k) {
            const bf16x8 a0 = *(const bf16x8*)(wb + a0base + k * 64);
            const bf16x8 a1 = *(const bf16x8*)(wb + a1base + k * 64);
            acc00 = __builtin_amdgcn_mfma_f32_16x16x32_bf16(a0, b[0][k], acc00, 0, 0, 0);
            acc01 = __builtin_amdgcn_mfma_f32_16x16x32_bf16(a0, b[1][k], acc01, 0, 0, 0);
            acc10 = __builtin_amdgcn_mfma_f32_16x16x32_bf16(a1, b[0][k], acc10, 0, 0, 0);
            acc11 = __builtin_amdgcn_mfma_f32_16x16x32_bf16(a1, b[1][k], acc11, 0, 0, 0);
        }

        // weight phase for s+1 into the other buffer
        if (haveN) {
            bf16x8 wv8 = wcompute(alo0, ahi0, hlo0, hhi0, hsv0, lsum0);
            *(bf16x8*)(wn + w0off) = wv8;
            if (has2) {
                wv8 = wcompute(alo1, ahi1, hlo1, hhi1, hsv1, lsum1);
                *(bf16x8*)(wn + w1off) = wv8;
            }
        }

        asm volatile("s_waitcnt lgkmcnt(0)" ::: "memory");
        __builtin_amdgcn_s_barrier();
    }

    // ---- row sums: LDS accumulate then one global atomic per row
    atomicAdd(&lrow[r0], lsum0);
    if (has2) atomicAdd(&lrow[r1], lsum1);
    __syncthreads();
    if (t < BM) atomicAdd(&lg[i0 + t], lrow[t]);

    // ---- numerator: NSPLIT atomic contributions per element
    #pragma unroll
    for (int g = 0; g < 4; ++g) {
        const int rr = asl * 4 + g;
        atomicAdd(&out[(size_t)(i0 + rr) * FD + wv * 32 + al],           acc00[g]);
        atomicAdd(&out[(size_t)(i0 + rr) * FD + wv * 32 + 16 + al],      acc01[g]);
        atomicAdd(&out[(size_t)(i0 + 16 + rr) * FD + wv * 32 + al],      acc10[g]);
        atomicAdd(&out[(size_t)(i0 + 16 + rr) * FD + wv * 32 + 16 + al], acc11[g]);
    }
}

// ---------------- K4: normalize by row sums ----------------
__global__ __launch_bounds__(256) void k_norm(float* __restrict__ out,
                                              const float* __restrict__ lg) {
    const int i = blockIdx.x;
    const float rinv = 1.0f / lg[i];
    out[(size_t)i * FD + threadIdx.x] *= rinv;
}

extern "C" void kernel_launch(void* const* d_in, const int* in_sizes, int n_in,
                              void* d_out, int out_size, void* d_ws, size_t ws_size,
                              hipStream_t stream) {
    const float* X     = (const float*)d_in[0];
    const int*   adj   = (const int*)d_in[1];
    const float* Ww    = (const float*)d_in[2];
    const float* Wb    = (const float*)d_in[3];
    const float* a_src = (const float*)d_in[4];
    const float* a_dst = (const float*)d_in[5];
    const float* a_b   = (const float*)d_in[6];
    float* out = (float*)d_out;

    bf16*  Ht = (bf16*)d_ws;                                  // 4.096 MB
    float* hs = (float*)((char*)d_ws + (size_t)FD * NN * sizeof(bf16));
    float* hd = hs + NN;
    float* lg = hd + NN;

    hipMemsetAsync(out, 0, (size_t)NN * FD * sizeof(float), stream);
    hipMemsetAsync(lg, 0, NN * sizeof(float), stream);

    k_linear<<<NN / 16, 256, 0, stream>>>(X, Ww, Wb, Ht);
    k_attn_vec<<<NN / 64, 256, 0, stream>>>(Ht, a_src, a_dst, a_b, hs, hd);
    k_gat<<<(NN / BM) * NSPLIT, 512, 0, stream>>>(Ht, adj, hs, hd, out, lg);
    k_norm<<<NN, 256, 0, stream>>>(out, lg);
}